// Round 2
// baseline (940.899 us; speedup 1.0000x reference)
//
#include <hip/hip_runtime.h>

#define NSEQ   64
#define KVH    8
#define G      4            // query heads per kv head
#define NH     32           // query heads total
#define D      128
#define BS     16           // cache block size (tokens)
#define MAXBLK 128          // blocks per seq
#define MAXCTX 2048
#define TPP    128          // tokens per partition (one wave per partition)
#define MAXP   (MAXCTX / TPP)   // 16
#define SCALE  0.08838834764831845f

// ---------------------------------------------------------------------------
// Kernel 1: reshape_and_cache — scatter the new token's K/V into the paged
// caches. 64 blocks x 256 threads; one block per sequence.
// ---------------------------------------------------------------------------
__global__ __launch_bounds__(256) void scatter_kv(
    const float* __restrict__ knew, const float* __restrict__ vnew,
    float* __restrict__ kc, float* __restrict__ vc,
    const int* __restrict__ slot_mapping) {
  const int s = blockIdx.x;
  const int t = threadIdx.x;               // 0..255
  const int slot = slot_mapping[s];
  const int blk = slot >> 4;
  const int off = slot & (BS - 1);
  const int h = t >> 5;                    // kv head 0..7
  const int d = (t & 31) << 2;             // dim 0..124 step 4
  const int src = (s * KVH + h) * D + d;
  const int dst = (((blk * KVH + h) * BS + off) * D) + d;
  *(float4*)(kc + dst) = *(const float4*)(knew + src);
  *(float4*)(vc + dst) = *(const float4*)(vnew + src);
}

// ---------------------------------------------------------------------------
// Kernel 2: split-K partial attention. One WAVE per (seq, kvh, partition).
// 16 lanes per token, 4 tokens per iteration. Lane l = (tgrp = l>>4,
// j = l&15); lane owns dims {j*4 + c*64, c=0,1}. Each load instruction is
// 4 x 256B contiguous segments (fully coalesced 1KB). Dot reduce = 4-stage
// shfl_xor within 16-lane groups; online softmax per token-group; 2-stage
// butterfly merge (xor 16, 32) at the end. Fully-masked groups are killed
// at merge by exp(-1e30 - m_valid) == 0 (sentinel is finite: no inf-inf).
// ---------------------------------------------------------------------------
__global__ __launch_bounds__(256, 4) void attn_partial(
    const float* __restrict__ query,
    const float* __restrict__ kc, const float* __restrict__ vc,
    const int* __restrict__ block_tables, const int* __restrict__ ctx_lens,
    float* __restrict__ ws_o,   // [NSEQ*KVH*MAXP][G][D]
    float* __restrict__ ws_ml)  // [NSEQ*KVH*MAXP][8] = m[4], l[4]
{
  const int wave = (blockIdx.x << 2) + (threadIdx.x >> 6);
  const int part = wave & (MAXP - 1);
  const int kvh  = (wave >> 4) & (KVH - 1);
  const int seq  = wave >> 7;
  const int ctx  = ctx_lens[seq];
  const int base = part * TPP;
  if (base >= ctx) return;                       // inactive partition
  const int nt = min(TPP, ctx - base);           // valid tokens here

  const int lane = threadIdx.x & 63;
  const int tgrp = lane >> 4;                    // token group 0..3
  const int j    = lane & 15;                    // sublane
  const int joff = j << 2;                       // float offset in 64-chunk

  // Q fragments for the 4 grouped heads, pre-scaled by 1/sqrt(D)
  float4 q[G][2];
#pragma unroll
  for (int g = 0; g < G; ++g) {
    const float* qp = query + (seq * NH + kvh * G + g) * D + joff;
#pragma unroll
    for (int c = 0; c < 2; ++c) {
      float4 t = *(const float4*)(qp + c * 64);
      q[g][c] = make_float4(t.x * SCALE, t.y * SCALE, t.z * SCALE, t.w * SCALE);
    }
  }

  float  m[G], l[G];
  float4 o[G][2];
#pragma unroll
  for (int g = 0; g < G; ++g) {
    m[g] = -1e30f; l[g] = 0.f;
    o[g][0] = make_float4(0.f, 0.f, 0.f, 0.f);
    o[g][1] = make_float4(0.f, 0.f, 0.f, 0.f);
  }

  const int* bt = block_tables + seq * MAXBLK;
  const int niter = (nt + 3) >> 2;

  for (int i = 0; i < niter; ++i) {
    const int tl = (i << 2) + tgrp;              // local token for this group
    const int tg = base + tl;                    // global position (< MAXCTX)
    const int cb = bt[tg >> 4];                  // wave-uniform (4 tok/blk)
    const int row = ((cb * KVH + kvh) * BS + (tg & (BS - 1))) * D;

    const float4 k0 = *(const float4*)(kc + row + joff);
    const float4 k1 = *(const float4*)(kc + row + 64 + joff);
    const float4 v0 = *(const float4*)(vc + row + joff);
    const float4 v1 = *(const float4*)(vc + row + 64 + joff);

    float sc[G];
#pragma unroll
    for (int g = 0; g < G; ++g) {
      float a = q[g][0].x * k0.x + q[g][0].y * k0.y
              + q[g][0].z * k0.z + q[g][0].w * k0.w;
      float b = q[g][1].x * k1.x + q[g][1].y * k1.y
              + q[g][1].z * k1.z + q[g][1].w * k1.w;
      float s = a + b;
      s += __shfl_xor(s, 1);
      s += __shfl_xor(s, 2);
      s += __shfl_xor(s, 4);
      s += __shfl_xor(s, 8);                     // full score in all 16 lanes
      sc[g] = (tl < nt) ? s : -1e30f;
    }
#pragma unroll
    for (int g = 0; g < G; ++g) {
      const float mn = fmaxf(m[g], sc[g]);
      const float r  = __expf(m[g] - mn);        // rescale old state
      const float p  = __expf(sc[g] - mn);       // this token's weight
      m[g] = mn;
      l[g] = l[g] * r + p;
      o[g][0].x = o[g][0].x * r + p * v0.x;
      o[g][0].y = o[g][0].y * r + p * v0.y;
      o[g][0].z = o[g][0].z * r + p * v0.z;
      o[g][0].w = o[g][0].w * r + p * v0.w;
      o[g][1].x = o[g][1].x * r + p * v1.x;
      o[g][1].y = o[g][1].y * r + p * v1.y;
      o[g][1].z = o[g][1].z * r + p * v1.z;
      o[g][1].w = o[g][1].w * r + p * v1.w;
    }
  }

  // merge the 4 token-group softmax states: butterfly over strides 16, 32
#pragma unroll
  for (int st = 0; st < 2; ++st) {
    const int S = 16 << st;
#pragma unroll
    for (int g = 0; g < G; ++g) {
      const float mo = __shfl_xor(m[g], S);
      const float lo = __shfl_xor(l[g], S);
      float4 oo0, oo1;
      oo0.x = __shfl_xor(o[g][0].x, S);
      oo0.y = __shfl_xor(o[g][0].y, S);
      oo0.z = __shfl_xor(o[g][0].z, S);
      oo0.w = __shfl_xor(o[g][0].w, S);
      oo1.x = __shfl_xor(o[g][1].x, S);
      oo1.y = __shfl_xor(o[g][1].y, S);
      oo1.z = __shfl_xor(o[g][1].z, S);
      oo1.w = __shfl_xor(o[g][1].w, S);
      const float mn = fmaxf(m[g], mo);
      const float a  = __expf(m[g] - mn);
      const float b  = __expf(mo  - mn);
      m[g] = mn;
      l[g] = l[g] * a + lo * b;
      o[g][0].x = o[g][0].x * a + oo0.x * b;
      o[g][0].y = o[g][0].y * a + oo0.y * b;
      o[g][0].z = o[g][0].z * a + oo0.z * b;
      o[g][0].w = o[g][0].w * a + oo0.w * b;
      o[g][1].x = o[g][1].x * a + oo1.x * b;
      o[g][1].y = o[g][1].y * a + oo1.y * b;
      o[g][1].z = o[g][1].z * a + oo1.z * b;
      o[g][1].w = o[g][1].w * a + oo1.w * b;
    }
  }

  if (tgrp == 0) {                               // lanes 0..15 hold merged state
    float* op = ws_o + (size_t)wave * (G * D);
#pragma unroll
    for (int g = 0; g < G; ++g) {
      *(float4*)(op + g * D + joff)      = o[g][0];
      *(float4*)(op + g * D + 64 + joff) = o[g][1];
    }
    if (j < G) {   // lanes 0..3: m/l for head j (static-index select)
      const float mv = (j == 0) ? m[0] : (j == 1) ? m[1] : (j == 2) ? m[2] : m[3];
      const float lv = (j == 0) ? l[0] : (j == 1) ? l[1] : (j == 2) ? l[2] : l[3];
      ws_ml[wave * 8 + j]     = mv;
      ws_ml[wave * 8 + 4 + j] = lv;
    }
  }
}

// ---------------------------------------------------------------------------
// Kernel 3: combine partition partials. One block per (seq, kvh);
// 512 threads = (g, d). Reads <=16 partials, writes final fp32 output.
// ---------------------------------------------------------------------------
__global__ __launch_bounds__(512) void attn_reduce(
    const float* __restrict__ ws_o, const float* __restrict__ ws_ml,
    const int* __restrict__ ctx_lens, float* __restrict__ out) {
  const int sk  = blockIdx.x;                 // seq*KVH + kvh
  const int seq = sk >> 3;
  const int kvh = sk & (KVH - 1);
  const int ctx = ctx_lens[seq];
  const int np  = (ctx + TPP - 1) / TPP;
  const int tid = threadIdx.x;
  const int g   = tid >> 7;
  const int d   = tid & (D - 1);
  const int wb  = sk * MAXP;

  float M = -1e30f;
  for (int p = 0; p < np; ++p)
    M = fmaxf(M, ws_ml[(wb + p) * 8 + g]);
  float L = 0.f;
  float acc = 0.f;
  for (int p = 0; p < np; ++p) {
    const float w = __expf(ws_ml[(wb + p) * 8 + g] - M);
    L   += w * ws_ml[(wb + p) * 8 + 4 + g];
    acc += w * ws_o[(size_t)(wb + p) * (G * D) + g * D + d];
  }
  out[seq * (NH * D) + (kvh * G + g) * D + d] = acc / L;
}

// ---------------------------------------------------------------------------
extern "C" void kernel_launch(void* const* d_in, const int* in_sizes, int n_in,
                              void* d_out, int out_size, void* d_ws, size_t ws_size,
                              hipStream_t stream) {
  const float* query = (const float*)d_in[0];
  const float* knew  = (const float*)d_in[1];
  const float* vnew  = (const float*)d_in[2];
  float*       kc    = (float*)d_in[3];        // updated in place (harness restores)
  float*       vc    = (float*)d_in[4];
  const int*   bt    = (const int*)d_in[5];
  const int*   cl    = (const int*)d_in[6];
  const int*   sm    = (const int*)d_in[7];
  float*       out   = (float*)d_out;

  float* ws_o  = (float*)d_ws;                              // 8192*512 f32 = 16 MiB
  float* ws_ml = ws_o + (size_t)NSEQ * KVH * MAXP * G * D;  // 8192*8 f32 = 256 KiB

  scatter_kv<<<NSEQ, 256, 0, stream>>>(knew, vnew, kc, vc, sm);
  attn_partial<<<(NSEQ * KVH * MAXP) / 4, 256, 0, stream>>>(
      query, kc, vc, bt, cl, ws_o, ws_ml);
  attn_reduce<<<NSEQ * KVH, 512, 0, stream>>>(ws_o, ws_ml, cl, out);
}